// Round 2
// baseline (597.479 us; speedup 1.0000x reference)
//
#include <hip/hip_runtime.h>
#include <cstdint>
#include <cstddef>

#define NN 512
#define MM 256
#define ZT 1e-9f
#define CAP 16384      // CSR capacity (nnz ~6.2K / ~7.9K)
#define NPLANES 216    // 24 L1 planes + 192 L2 planes
#define LSTRIDE 18     // padded LDS row stride for 16-wide batch tiles

// ---------------- CSR build: one wave per row ----------------
__global__ __launch_bounds__(256) void k_csr_count(const float* __restrict__ S,
                                                   int* __restrict__ sp_cnt,
                                                   int* __restrict__ s_cnt) {
  int wid = (blockIdx.x * 256 + threadIdx.x) >> 6;
  int lane = threadIdx.x & 63;
  if (wid >= NN) return;
  int m = wid;
  int csp = 0, cs = 0;
  for (int ch = 0; ch < NN / 64; ++ch) {
    int n = ch * 64 + lane;
    float s = S[(size_t)m * NN + n];
    bool ps  = (s != 0.0f);
    bool psp = ((fabsf(s) + ((m == n) ? 1.0f : 0.0f)) > ZT) && !((m >= MM) && (n >= MM));
    csp += __popcll(__ballot(psp));
    cs  += __popcll(__ballot(ps));
  }
  if (lane == 0) { sp_cnt[m] = csp; s_cnt[m] = cs; }
}

__global__ void k_prefix(int* __restrict__ sp_ptr, int* __restrict__ s_ptr,
                         const int* __restrict__ sp_cnt, const int* __restrict__ s_cnt) {
  int lane = threadIdx.x;  // 64 threads, one wave
  int c0[8], c1[8]; int t0 = 0, t1 = 0;
  for (int i = 0; i < 8; ++i) {
    c0[i] = sp_cnt[lane * 8 + i]; t0 += c0[i];
    c1[i] = s_cnt[lane * 8 + i];  t1 += c1[i];
  }
  int i0 = t0, i1 = t1;
  for (int d = 1; d < 64; d <<= 1) {
    int x0 = __shfl_up(i0, d), x1 = __shfl_up(i1, d);
    if (lane >= d) { i0 += x0; i1 += x1; }
  }
  int e0 = i0 - t0, e1 = i1 - t1;
  for (int i = 0; i < 8; ++i) {
    sp_ptr[lane * 8 + i] = e0; e0 += c0[i];
    s_ptr[lane * 8 + i]  = e1; e1 += c1[i];
  }
  if (lane == 63) { sp_ptr[NN] = e0; s_ptr[NN] = e1; }
}

__global__ __launch_bounds__(256) void k_csr_fill(const float* __restrict__ S,
    const int* __restrict__ sp_ptr, const int* __restrict__ s_ptr,
    int* __restrict__ sp_cols, int* __restrict__ sp_rows,
    int* __restrict__ s_cols, int* __restrict__ s_rows, float* __restrict__ s_vals) {
  int wid = (blockIdx.x * 256 + threadIdx.x) >> 6;
  int lane = threadIdx.x & 63;
  if (wid >= NN) return;
  int m = wid;
  int bsp = sp_ptr[m], bs = s_ptr[m];
  unsigned long long lt = (1ull << lane) - 1ull;
  for (int ch = 0; ch < NN / 64; ++ch) {
    int n = ch * 64 + lane;
    float s = S[(size_t)m * NN + n];
    bool ps  = (s != 0.0f);
    bool psp = ((fabsf(s) + ((m == n) ? 1.0f : 0.0f)) > ZT) && !((m >= MM) && (n >= MM));
    unsigned long long msp = __ballot(psp), ms = __ballot(ps);
    if (psp) { int p = bsp + __popcll(msp & lt); if (p < CAP) { sp_cols[p] = n; sp_rows[p] = m; } }
    if (ps)  { int p = bs  + __popcll(ms  & lt); if (p < CAP) { s_cols[p] = n; s_rows[p] = m; s_vals[p] = s; } }
    bsp += __popcll(msp); bs += __popcll(ms);
  }
}

// ---------------- pack masked weights: wpk[p][j] = plane_p[rv[j]*512+cv[j]] ----
__global__ __launch_bounds__(1024) void k_gather(
    const float* __restrict__ wEV1, const float* __restrict__ wEV2,
    const int* __restrict__ sp_ptr, const int* __restrict__ sp_cols,
    const int* __restrict__ sp_rows, float* __restrict__ wpk) {
  int p = blockIdx.y;
  int nnz = sp_ptr[NN];
  const float* src = (p < 24) ? (wEV1 + ((size_t)p << 18))
                              : (wEV2 + ((size_t)(p - 24) << 18));
  float* dst = wpk + (size_t)p * CAP;
  for (int j = blockIdx.x * 1024 + threadIdx.x; j < nnz; j += 4096) {
    int cv = sp_cols[j], rv = sp_rows[j];
    dst[j] = src[((size_t)rv << 9) + cv];
  }
}

// ---------------- x transpose: (B,N) -> (N,B) ----------------
__global__ __launch_bounds__(256) void k_transpose(const float* __restrict__ x,
                                                   float* __restrict__ xt) {
  int tid = blockIdx.x * 256 + threadIdx.x;   // 0..32767
  int n = tid >> 6, b = tid & 63;
  xt[tid] = x[(size_t)b * NN + n];
}

// ---------------- fused per-chain layer kernel ----------------
// EV block (bid < nEV): c = bid>>2 chain, q = bid&3 batch quarter.
//   LDS-resident 3-step chain: z^{k+1} = Phi_k z^k, acc = sum_k z^k -> zsum[c].
// LSI block: g = (bid-nEV)>>2: u1 = S zin_g, u2 = S u1 -> uo1/uo2[g].
// 512 threads = 8 waves; 32 processors (wave,subgroup), 16 rows each, batch=16 lanes.
__global__ __launch_bounds__(512) void k_layer(
    const float* __restrict__ wpk,
    const int* __restrict__ sp_ptr, const int* __restrict__ sp_cols,
    const int* __restrict__ sp_rows,
    const float* __restrict__ s_vals, const int* __restrict__ s_ptr,
    const int* __restrict__ s_cols, const int* __restrict__ s_rows,
    const float* __restrict__ zin,
    float* __restrict__ zsum,
    float* __restrict__ uo1, float* __restrict__ uo2,
    int Gshift, int nEV, int wpk_base) {
  __shared__ float zA[NN * LSTRIDE];
  __shared__ float zB[NN * LSTRIDE];
  int tid = threadIdx.x;
  int wave = tid >> 6, lane = tid & 63;
  int sub = lane >> 4, b = lane & 15;
  int P = wave * 4 + sub;            // 0..31
  int r0 = P * 16, rend = r0 + 16;
  bool isEV = ((int)blockIdx.x < nEV);
  int G = 1 << Gshift;
  int c = 0, q, f = 0, g;
  if (isEV) { c = blockIdx.x >> 2; q = blockIdx.x & 3; f = c >> Gshift; g = c & (G - 1); }
  else      { int lb = blockIdx.x - nEV; g = lb >> 2; q = lb & 3; }

  // stage input quarter (batch cols q*16..q*16+15) into LDS
  const float* zp = zin + ((size_t)g << 15);
  for (int t = tid; t < NN * 16; t += 512) {
    int n = t >> 4, bb = t & 15;
    zA[n * LSTRIDE + bb] = zp[(n << 6) + (q << 4) + bb];
  }
  __syncthreads();
  float* zCur = zA; float* zNxt = zB;

  if (isEV) {
    float acc[16];
#pragma unroll
    for (int i = 0; i < 16; ++i) acc[i] = 0.f;
    for (int k = 0; k < 3; ++k) {
      const float* wp = wpk + (size_t)(wpk_base + (((f * 3 + k) << Gshift) + g)) * CAP;
      int j0 = sp_ptr[r0], j1 = sp_ptr[rend];
      int r = r0; float racc = 0.f;
      for (int jb = j0; jb < j1; jb += 8) {
        int cc[8], rr[8]; float ww[8];
#pragma unroll
        for (int i = 0; i < 8; ++i) {
          int j = jb + i;
          bool v = (j < j1);
          int js = v ? j : (j1 - 1);
          cc[i] = sp_cols[js] * LSTRIDE;
          rr[i] = v ? sp_rows[js] : (rend - 1);
          ww[i] = v ? wp[js] : 0.f;
        }
#pragma unroll
        for (int i = 0; i < 8; ++i) {
          while (r < rr[i]) { zNxt[r * LSTRIDE + b] = racc; racc = 0.f; ++r; }
          racc += ww[i] * zCur[cc[i] + b];
        }
      }
      while (r < rend) { zNxt[r * LSTRIDE + b] = racc; racc = 0.f; ++r; }
      __syncthreads();
#pragma unroll
      for (int i = 0; i < 16; ++i) {
        int s = i * 512 + tid;
        acc[i] += zNxt[(s >> 4) * LSTRIDE + (s & 15)];
      }
      float* t2 = zCur; zCur = zNxt; zNxt = t2;  // writes of next k hit retired buffer
    }
    float* zo = zsum + ((size_t)c << 15);
#pragma unroll
    for (int i = 0; i < 16; ++i) {
      int s = i * 512 + tid;
      zo[((s >> 4) << 6) + (q << 4) + (s & 15)] = acc[i];
    }
  } else {
    for (int step = 0; step < 2; ++step) {
      int j0 = s_ptr[r0], j1 = s_ptr[rend];
      int r = r0; float racc = 0.f;
      for (int jb = j0; jb < j1; jb += 8) {
        int cc[8], rr[8]; float ww[8];
#pragma unroll
        for (int i = 0; i < 8; ++i) {
          int j = jb + i;
          bool v = (j < j1);
          int js = v ? j : (j1 - 1);
          cc[i] = s_cols[js] * LSTRIDE;
          rr[i] = v ? s_rows[js] : (rend - 1);
          ww[i] = v ? s_vals[js] : 0.f;
        }
#pragma unroll
        for (int i = 0; i < 8; ++i) {
          while (r < rr[i]) { zNxt[r * LSTRIDE + b] = racc; racc = 0.f; ++r; }
          racc += ww[i] * zCur[cc[i] + b];
        }
      }
      while (r < rend) { zNxt[r * LSTRIDE + b] = racc; racc = 0.f; ++r; }
      __syncthreads();
      float* up = (step ? uo2 : uo1) + ((size_t)g << 15);
      for (int t = tid; t < NN * 16; t += 512) {
        int n = t >> 4, bb = t & 15;
        up[(n << 6) + (q << 4) + bb] = zNxt[n * LSTRIDE + bb];
      }
      float* t2 = zCur; zCur = zNxt; zNxt = t2;
    }
  }
}

// ---------------- layer combines ----------------
__global__ __launch_bounds__(256) void k_y1(const float* __restrict__ zs,
    const float* __restrict__ xt, const float* __restrict__ u1, const float* __restrict__ u2,
    const float* __restrict__ wLSI1, const float* __restrict__ b1, float* __restrict__ y1) {
  int tid = blockIdx.x * 256 + threadIdx.x;   // 0..262143
  int f = tid >> 15, mb = tid & ((NN << 6) - 1);
  float r = zs[tid];
  r += wLSI1[f * 3 + 0] * xt[mb] + wLSI1[f * 3 + 1] * u1[mb] + wLSI1[f * 3 + 2] * u2[mb];
  y1[tid] = r + b1[f];
}

__global__ __launch_bounds__(256) void k_y2(const float* __restrict__ zs,
    const float* __restrict__ y1, const float* __restrict__ v1, const float* __restrict__ v2,
    const float* __restrict__ wLSI2, const float* __restrict__ b2, float* __restrict__ y2) {
  int tid = blockIdx.x * 256 + threadIdx.x;   // 0..262143
  int f = tid >> 15, mb = tid & ((NN << 6) - 1);
  float r = b2[f];
#pragma unroll
  for (int g = 0; g < 8; ++g) {
    r += zs[((size_t)(f * 8 + g) << 15) + mb];
    size_t gc = ((size_t)g << 15) + mb;
    r += wLSI2[f * 24 + g] * y1[gc] + wLSI2[f * 24 + 8 + g] * v1[gc] + wLSI2[f * 24 + 16 + g] * v2[gc];
  }
  y2[tid] = r;
}

// ---------------- readout GEMMs ----------------
__global__ __launch_bounds__(256) void k_init_ht(const float* __restrict__ bW1,
                                                 float* __restrict__ ht) {
  int tid = blockIdx.x * 256 + threadIdx.x;   // 0..32767
  ht[tid] = bW1[tid >> 6];
}

__global__ __launch_bounds__(256) void k_gemm1(const float* __restrict__ W1,
                                               const float* __restrict__ y2,
                                               float* __restrict__ ht) {
  int wid = (blockIdx.x * 256 + threadIdx.x) >> 6;  // 0..511
  int lane = threadIdx.x & 63;
  int pg = wid >> 3;
  int q0 = (wid & 7) << 9;
  float acc[8] = {0, 0, 0, 0, 0, 0, 0, 0};
  const float* Wp = W1 + (size_t)(pg * 8) * 4096;
  for (int q = q0; q < q0 + 512; q += 4) {
#pragma unroll
    for (int u = 0; u < 4; ++u) {
      float v = y2[(size_t)(q + u) * 64 + lane];
#pragma unroll
      for (int p = 0; p < 8; ++p) acc[p] += Wp[(size_t)p * 4096 + q + u] * v;
    }
  }
#pragma unroll
  for (int p = 0; p < 8; ++p) atomicAdd(&ht[(size_t)(pg * 8 + p) * 64 + lane], acc[p]);
}

__global__ __launch_bounds__(256) void k_gemm2(const float* __restrict__ W2,
                                               const float* __restrict__ bW2,
                                               const float* __restrict__ ht,
                                               float* __restrict__ out) {
  int wid = (blockIdx.x * 256 + threadIdx.x) >> 6;  // 0..127
  int lane = threadIdx.x & 63;
  float acc = 0.f;
  for (int p = 0; p < 512; p += 4) {
#pragma unroll
    for (int u = 0; u < 4; ++u) acc += W2[(size_t)wid * 512 + p + u] * ht[(size_t)(p + u) * 64 + lane];
  }
  out[(size_t)lane * 128 + wid] = acc + bW2[wid];
}

extern "C" void kernel_launch(void* const* d_in, const int* in_sizes, int n_in,
                              void* d_out, int out_size, void* d_ws, size_t ws_size,
                              hipStream_t stream) {
  const float* x     = (const float*)d_in[0];
  const float* S     = (const float*)d_in[1];
  const float* wEV1  = (const float*)d_in[2];
  const float* wLSI1 = (const float*)d_in[3];
  const float* b1    = (const float*)d_in[4];
  const float* wEV2  = (const float*)d_in[5];
  const float* wLSI2 = (const float*)d_in[6];
  const float* b2    = (const float*)d_in[7];
  const float* W1    = (const float*)d_in[8];
  const float* bW1   = (const float*)d_in[9];
  const float* W2    = (const float*)d_in[10];
  const float* bW2   = (const float*)d_in[11];
  float* out = (float*)d_out;

  char* w = (char*)d_ws;
  auto alloc = [&](size_t bytes) { char* p = w; w += (bytes + 255) & ~(size_t)255; return p; };
  int*   sp_cnt  = (int*)alloc(512 * 4);
  int*   s_cnt   = (int*)alloc(512 * 4);
  int*   sp_ptr  = (int*)alloc(513 * 4);
  int*   s_ptr   = (int*)alloc(513 * 4);
  int*   sp_cols = (int*)alloc(CAP * 4);
  int*   sp_rows = (int*)alloc(CAP * 4);
  int*   s_cols  = (int*)alloc(CAP * 4);
  int*   s_rows  = (int*)alloc(CAP * 4);
  float* s_vals  = (float*)alloc(CAP * 4);
  float* wpk     = (float*)alloc((size_t)NPLANES * CAP * 4);   // 14.2 MB
  float* xt      = (float*)alloc((size_t)(NN << 6) * 4);
  float* u1      = (float*)alloc((size_t)(NN << 6) * 4);
  float* u2      = (float*)alloc((size_t)(NN << 6) * 4);
  float* y1      = (float*)alloc((size_t)8 * (NN << 6) * 4);
  float* v1      = (float*)alloc((size_t)8 * (NN << 6) * 4);
  float* v2      = (float*)alloc((size_t)8 * (NN << 6) * 4);
  float* y2      = (float*)alloc((size_t)8 * (NN << 6) * 4);
  float* ht      = (float*)alloc((size_t)(NN << 6) * 4);
  float* z1sum   = (float*)alloc((size_t)8 * (NN << 6) * 4);
  float* z2sum   = (float*)alloc((size_t)64 * (NN << 6) * 4);  // 8.4 MB
  (void)ws_size; (void)in_sizes; (void)n_in; (void)out_size;

  // CSR build + weight packing
  k_csr_count<<<128, 256, 0, stream>>>(S, sp_cnt, s_cnt);
  k_prefix<<<1, 64, 0, stream>>>(sp_ptr, s_ptr, sp_cnt, s_cnt);
  k_csr_fill<<<128, 256, 0, stream>>>(S, sp_ptr, s_ptr, sp_cols, sp_rows, s_cols, s_rows, s_vals);
  k_gather<<<dim3(4, NPLANES), 1024, 0, stream>>>(wEV1, wEV2, sp_ptr, sp_cols, sp_rows, wpk);
  k_transpose<<<128, 256, 0, stream>>>(x, xt);

  // layer 1: 8 EV chains x 4 quarters + 1 LSI chain x 4 quarters
  k_layer<<<36, 512, 0, stream>>>(wpk, sp_ptr, sp_cols, sp_rows,
                                  s_vals, s_ptr, s_cols, s_rows,
                                  xt, z1sum, u1, u2, 0, 32, 0);
  k_y1<<<1024, 256, 0, stream>>>(z1sum, xt, u1, u2, wLSI1, b1, y1);

  // layer 2: 64 EV chains x 4 quarters + 8 LSI chains x 4 quarters
  k_layer<<<288, 512, 0, stream>>>(wpk, sp_ptr, sp_cols, sp_rows,
                                   s_vals, s_ptr, s_cols, s_rows,
                                   y1, z2sum, v1, v2, 3, 256, 24);
  k_y2<<<1024, 256, 0, stream>>>(z2sum, y1, v1, v2, wLSI2, b2, y2);

  // readout
  k_init_ht<<<128, 256, 0, stream>>>(bW1, ht);
  k_gemm1<<<128, 256, 0, stream>>>(W1, y2, ht);
  k_gemm2<<<32, 256, 0, stream>>>(W2, bW2, ht, out);
}